// Round 25
// baseline (63.895 us; speedup 1.0000x reference)
//
#include <hip/hip_runtime.h>
#include <cmath>

typedef float  f32x4  __attribute__((ext_vector_type(4)));
typedef __bf16 bf16x8 __attribute__((ext_vector_type(8)));
typedef unsigned int u32x4 __attribute__((ext_vector_type(4)));
typedef unsigned int u32x2 __attribute__((ext_vector_type(2)));
typedef unsigned int   u32;
typedef unsigned short u16;

#define HEAD_DIM 64
#define N_HEADS  25
#define N_KV     5
#define WINDOW   1024
#define N_META   128
#define B_       2
#define T_       2048
#define QB       64
#define NTILES   (T_ / 64)
#define TILE_U32 2048               // 64 rows x 32 u32 (8 KB)
// Constant softmax bias: S*0.125*log2e <= (8*1.5)^2*0.125*1.443 ~= 26 (RMSNorm-guaranteed,
// w in [0.5,1.5]). exp2(S-20) <= 64; l <= 6.6e4; min ~= 2^-46 (normal). Scale cancels in O/l.
#define SM_BIAS  (-20.0f)

static __device__ __forceinline__ u16 bf16_bits(float f) {
  __bf16 h = (__bf16)f;
  return __builtin_bit_cast(u16, h);
}
static __device__ __forceinline__ u32 pack2(float lo, float hi) {
  return ((u32)bf16_bits(hi) << 16) | bf16_bits(lo);
}
static __device__ __forceinline__ float fexp2(float x) {
  return __builtin_amdgcn_exp2f(x);    // bare v_exp_f32; exp2(-inf)=0
}
static __device__ __forceinline__ void gload16(const u32* g, u32* l) {
  __builtin_amdgcn_global_load_lds((const __attribute__((address_space(1))) u32*)g,
                                   (__attribute__((address_space(3))) u32*)l, 16, 0, 0);
}

// ---------------- Kernel 1 (merged prep): V-tiles (blk<320) + K 16-row waves (blk>=320) -
// K ws: [b][kvh][tile][key(64)][seg_phys(8) x 4 u32]; seg_phys = seg_log ^ (key&7)
// V ws: [b][kvh][tile][d(64)][32 u32]; col c=16a+8b+2g+e at seg (4a+g)^(d&7), slot 2b+e
__global__ __launch_bounds__(256) void prep_kernel(
    const float* __restrict__ k_in, const float* __restrict__ k_w,
    const float* __restrict__ v_in, const int* __restrict__ pos_ids,
    u32* __restrict__ k_ws, u32* __restrict__ v_ws)
{
  const int blk = blockIdx.x;
  const int tid = threadIdx.x;

  if (blk < B_ * N_KV * NTILES) {
    // ---------------- V transpose tile ----------------
    int tile = blk & (NTILES - 1);
    int bk   = blk >> 5;
    int kvh  = bk % N_KV, b = bk / N_KV;
    int t0   = tile * 64;

    __shared__ u16 Tl[64][72];           // [d][key]

    #pragma unroll
    for (int it = 0; it < 4; ++it) {
      int idx = it * 256 + tid;
      int kl = idx >> 4, dq = idx & 15;
      const float4 f = *(const float4*)&v_in[((size_t)(b * T_ + t0 + kl)) * (N_KV * HEAD_DIM) + kvh * HEAD_DIM + dq * 4];
      Tl[dq * 4 + 0][kl] = bf16_bits(f.x);
      Tl[dq * 4 + 1][kl] = bf16_bits(f.y);
      Tl[dq * 4 + 2][kl] = bf16_bits(f.z);
      Tl[dq * 4 + 3][kl] = bf16_bits(f.w);
    }
    __syncthreads();

    u32* outb = v_ws + (size_t)blk * TILE_U32;
    #pragma unroll
    for (int it = 0; it < 8; ++it) {
      int o = it * 256 + tid;
      int d = o >> 5, c = o & 31;
      u32 w = ((u32)Tl[d][2 * c + 1] << 16) | Tl[d][2 * c];
      int a = c >> 4, bs = (c >> 3) & 1, gp = (c >> 1) & 3, e = c & 1;
      int sp = (4 * a + gp) ^ (d & 7);
      outb[d * 32 + sp * 4 + 2 * bs + e] = w;
    }
    return;
  }

  // ---------------- K RMSNorm + RoPE, 16 rows per wave ----------------
  const int lane = tid & 63, wid = tid >> 6;
  const int l15 = lane & 15, g = lane >> 4;
  const int gw   = (blk - B_ * N_KV * NTILES) * 4 + wid;   // 0..1279
  const int bkvh = gw >> 7;                                // 0..9 = b*5+kvh
  const int sl   = gw & 127;
  const int b    = bkvh / N_KV, kvh = bkvh % N_KV;
  const int t0   = sl * 16;

  const int   jbase = (4 * l15) & 31;
  const float r32   = 0.74989420933f;                      // 10000^(-1/32)
  float fr[4];
  fr[0] = powf(10000.f, -(float)jbase * (1.f / 32.f));
  fr[1] = fr[0] * r32; fr[2] = fr[1] * r32; fr[3] = fr[2] * r32;

  const int t0g = b * T_ + t0;
  int pos_prev = pos_ids[t0g + g];
  float cc[4], sn[4], c4[4], s4[4];
  #pragma unroll
  for (int e = 0; e < 4; ++e) {
    sincosf((float)pos_prev * fr[e], &sn[e], &cc[e]);      // sincosf(x, sin*, cos*)
    sincosf(4.f * fr[e], &s4[e], &c4[e]);
  }
  const float4 wv = *(const float4*)&k_w[4 * l15];
  u32* outb = k_ws + ((size_t)bkvh * NTILES + (t0 >> 6)) * TILE_U32;
  const int klbase = t0 & 63;
  const int sp_c   = l15 >> 1;
  const int slot   = (2 * l15) & 3;

  #pragma unroll
  for (int it = 0; it < 4; ++it) {
    const int row = 4 * it + g;
    if (it) {
      int pos = pos_ids[t0g + row];
      if (__all(pos == pos_prev + 4)) {
        #pragma unroll
        for (int e = 0; e < 4; ++e) {
          float c2 = cc[e] * c4[e] - sn[e] * s4[e];
          sn[e] = sn[e] * c4[e] + cc[e] * s4[e];
          cc[e] = c2;
        }
      } else {
        #pragma unroll
        for (int e = 0; e < 4; ++e) sincosf((float)pos * fr[e], &sn[e], &cc[e]);
      }
      pos_prev = pos;
    }
    const float4 xv = *(const float4*)&k_in[((size_t)(t0g + row)) * (N_KV * HEAD_DIM) + kvh * HEAD_DIM + 4 * l15];
    float ss = xv.x * xv.x + xv.y * xv.y + xv.z * xv.z + xv.w * xv.w;
    ss += __shfl_xor(ss, 1); ss += __shfl_xor(ss, 2);
    ss += __shfl_xor(ss, 4); ss += __shfl_xor(ss, 8);
    const float rn = rsqrtf(ss * (1.f / 64.f) + 1e-6f);
    float y[4] = {wv.x * xv.x * rn, wv.y * xv.y * rn, wv.z * xv.z * rn, wv.w * xv.w * rn};
    float rv[4];
    #pragma unroll
    for (int e = 0; e < 4; ++e) {
      float part = __shfl_xor(y[e], 8);
      rv[e] = (l15 < 8) ? (y[e] * cc[e] - part * sn[e])
                        : (y[e] * cc[e] + part * sn[e]);   // NO scale on K
    }
    const int kl = klbase + row;
    const int sp = sp_c ^ (kl & 7);
    u32x2 w2;
    w2.x = pack2(rv[0], rv[1]);
    w2.y = pack2(rv[2], rv[3]);
    *(u32x2*)&outb[kl * 32 + sp * 4 + slot] = w2;
  }
}

// ---------------- Kernel 2: fused MFMA flash attention (V direct-from-L2, K dbuf) ------
// V fragments load straight from ws (L2-resident; FETCH=16.3MB proved) at the exact
// addresses staging would have copied -> bit-identical values, no layout risk. Deletes
// per tile: V staging, 8 LDS b128 reads, the mid-barrier. K double-buffered in 16KB LDS;
// ONE barrier/tile (drains K(i+1) gload_lds + all waves done reading K buf).
__global__ __launch_bounds__(256, 4) void attn_kernel(
    const float* __restrict__ q_in, const float* __restrict__ q_w,
    const int* __restrict__ pos_ids,
    const u32* __restrict__ kws, const u32* __restrict__ vws,
    float* __restrict__ out)
{
  // XCD-affinity decode (r14) + snake permutation (r24, neutral, kept).
  const int i  = blockIdx.x;
  const int x  = i & 7;
  int k = i >> 3;
  {
    const int row = k >> 5, col = k & 31;
    const int base = row * 32;
    const int span = (200 - base < 32) ? (200 - base) : 32;
    k = base + ((row & 1) ? (span - 1 - col) : col);
  }
  const int gA = (5 * x) >> 2;
  const int a0 = 200 * x - 160 * gA;
  const int nB = 40 + a0;
  int grp, j_;
  if (k < nB) { grp = gA + 1; j_ = k; }
  else        { grp = gA;     j_ = a0 + (k - nB); }
  const int qt  = 31 - j_ / 5;
  const int hh  = j_ % 5;
  const int b   = grp / 5;
  const int kvh = grp % 5;
  const int h   = kvh * 5 + hh;
  const int qb  = qt * QB;
  const int tid = threadIdx.x, wid = tid >> 6, lane = tid & 63;
  const int l15 = lane & 15, g = lane >> 4;
  const int qrow0 = wid * 16;

  __shared__ u32 Ks[2 * TILE_U32];       // K tiles, double-buffered (buf1 = Q staging)

  const int nt    = (qt <= 18) ? (qt + 1) : 19;
  const int shift = qt - 18;

  const size_t kvbase = ((size_t)(b * N_KV + kvh)) * NTILES * TILE_U32;
  const u32* kb = kws + kvbase;
  const u32* vb = vws + kvbase;

  // ---- prologue: issue K(0)->buf0 (Ks buf1 hosts Q staging) ----
  #pragma unroll
  for (int j = 0; j < 2; ++j) {
    int ci = (wid << 1) | j;
    gload16(kb + ci * 256 + lane * 4, &Ks[ci * 256]);
  }

  // ---- Q staging into Ks buf1, 4-rows-parallel ----
  {
    const int   jbase = (4 * l15) & 31;
    const float r32   = 0.74989420933f;            // 10000^(-1/32)
    float fr[4];
    fr[0] = powf(10000.f, -(float)jbase * (1.f / 32.f));
    fr[1] = fr[0] * r32; fr[2] = fr[1] * r32; fr[3] = fr[2] * r32;

    const int t0g = b * T_ + qb + qrow0;
    int pos_prev = pos_ids[t0g + g];
    float cc[4], sn[4], c4[4], s4[4];
    #pragma unroll
    for (int e = 0; e < 4; ++e) {
      sincosf((float)pos_prev * fr[e], &sn[e], &cc[e]);   // sincosf(x, sin*, cos*)
      sincosf(4.f * fr[e], &s4[e], &c4[e]);
    }
    const float4 wv = *(const float4*)&q_w[4 * l15];
    #pragma unroll
    for (int it = 0; it < 4; ++it) {
      const int row = 4 * it + g;
      if (it) {
        int pos = pos_ids[t0g + row];
        if (__all(pos == pos_prev + 4)) {
          #pragma unroll
          for (int e = 0; e < 4; ++e) {
            float c2 = cc[e] * c4[e] - sn[e] * s4[e];
            sn[e] = sn[e] * c4[e] + cc[e] * s4[e];
            cc[e] = c2;
          }
        } else {
          #pragma unroll
          for (int e = 0; e < 4; ++e) sincosf((float)pos * fr[e], &sn[e], &cc[e]);
        }
        pos_prev = pos;
      }
      const float4 xv = *(const float4*)&q_in[((size_t)(t0g + row)) * (N_HEADS * HEAD_DIM) + h * HEAD_DIM + 4 * l15];
      float ss = xv.x * xv.x + xv.y * xv.y + xv.z * xv.z + xv.w * xv.w;
      ss += __shfl_xor(ss, 1); ss += __shfl_xor(ss, 2);
      ss += __shfl_xor(ss, 4); ss += __shfl_xor(ss, 8);
      const float rn = rsqrtf(ss * (1.f / 64.f) + 1e-6f);
      float y[4] = {wv.x * xv.x * rn, wv.y * xv.y * rn, wv.z * xv.z * rn, wv.w * xv.w * rn};
      float rv[4];
      #pragma unroll
      for (int e = 0; e < 4; ++e) {
        float part = __shfl_xor(y[e], 8);
        rv[e] = ((l15 < 8) ? (y[e] * cc[e] - part * sn[e])
                           : (y[e] * cc[e] + part * sn[e])) * 0.18033688f;
      }
      u32x2 w2;
      w2.x = pack2(rv[0], rv[1]);
      w2.y = pack2(rv[2], rv[3]);
      *(u32x2*)&Ks[TILE_U32 + (qrow0 + row) * 32 + 2 * l15] = w2;
    }
  }
  __syncthreads();                       // K(0) drained + Q rows visible

  bf16x8 qf[2];
  #pragma unroll
  for (int ks = 0; ks < 2; ++ks)
    qf[ks] = *(const bf16x8*)&Ks[TILE_U32 + (qrow0 + l15) * 32 + 16 * ks + 4 * g];
  __syncthreads();                       // qf reads done before buf1 is overwritten

  // per-lane constant V fragment offsets (u32 idx) within a tile
  int voff[2][4];
  #pragma unroll
  for (int ks2 = 0; ks2 < 2; ++ks2)
    #pragma unroll
    for (int mt2 = 0; mt2 < 4; ++mt2)
      voff[ks2][mt2] = (16 * mt2 + l15) * 32 + (((4 * ks2 + g) ^ (l15 & 7)) << 2);

  f32x4 acc_o[4];
  #pragma unroll
  for (int mt = 0; mt < 4; ++mt) acc_o[mt] = (f32x4)(0.f);
  f32x4 acc_l = (f32x4)(0.f);            // l by MFMA: P x ones -> row q, replicated cols

  u32x4 onesw;
  onesw.x = 0x3F803F80u; onesw.y = 0x3F803F80u; onesw.z = 0x3F803F80u; onesw.w = 0x3F803F80u;
  const bf16x8 vones = __builtin_bit_cast(bf16x8, onesw);

  const int q_abs = qb + qrow0 + l15;

  for (int i2 = 0; i2 < nt; ++i2) {
    const int buf  = i2 & 1;
    const int tval = (qt <= 18 || i2 < 2) ? i2 : i2 + shift;
    const int k0   = tval << 6;

    // ---- issue V(i2) fragment loads (global, L2-hit); consumed after softmax ----
    const u32* vtile = vb + (size_t)tval * TILE_U32;
    bf16x8 vf[2][4];
    #pragma unroll
    for (int ks2 = 0; ks2 < 2; ++ks2)
      #pragma unroll
      for (int mt2 = 0; mt2 < 4; ++mt2)
        vf[ks2][mt2] = *(const bf16x8*)&vtile[voff[ks2][mt2]];

    // ---- issue K(i2+1) prefetch into buf^1 ----
    if (i2 + 1 < nt) {
      int tn = (qt <= 18 || i2 + 1 < 2) ? (i2 + 1) : (i2 + 1 + shift);
      const u32* kt = kb + (size_t)tn * TILE_U32;
      u32* kd = &Ks[(buf ^ 1) * TILE_U32];
      #pragma unroll
      for (int j = 0; j < 2; ++j) {
        int ci = (wid << 1) | j;
        gload16(kt + ci * 256 + lane * 4, kd + ci * 256);
      }
    }

    // ---- S^T - 20 = K·Q^T + C(-20) ----
    f32x4 accs[4];
    #pragma unroll
    for (int mt = 0; mt < 4; ++mt) accs[mt] = (f32x4)(SM_BIAS);
    #pragma unroll
    for (int ks = 0; ks < 2; ++ks) {
      #pragma unroll
      for (int mt = 0; mt < 4; ++mt) {
        bf16x8 kf = *(const bf16x8*)&Ks[buf * TILE_U32 + (16 * mt + l15) * 32 + (((4 * ks + g) ^ (l15 & 7)) << 2)];
        accs[mt] = __builtin_amdgcn_mfma_f32_16x16x32_bf16(kf, qf[ks], accs[mt], 0, 0, 0);
      }
    }

    // ---- mask boundary tiles, then P = exp2(S - 20) ----
    const bool do_mask = (i2 == nt - 1) || (qt >= 18 && i2 == 2);
    if (do_mask) {
      #pragma unroll
      for (int mt = 0; mt < 4; ++mt)
        #pragma unroll
        for (int rg = 0; rg < 4; ++rg) {
          int key = k0 + 16 * mt + 4 * g + rg;
          bool ok = (key <= q_abs) && ((key >= q_abs - (WINDOW - 1)) || (key < N_META));
          accs[mt][rg] = ok ? accs[mt][rg] : -INFINITY;
        }
    }
    #pragma unroll
    for (int mt = 0; mt < 4; ++mt)
      #pragma unroll
      for (int rg = 0; rg < 4; ++rg)
        accs[mt][rg] = fexp2(accs[mt][rg]);      // exp2(-inf) = 0 for masked

    // ---- O += P·V, l += P·1 (V from registers, loaded at tile start) ----
    #pragma unroll
    for (int ks2 = 0; ks2 < 2; ++ks2) {
      const int m0 = 2 * ks2, m1 = 2 * ks2 + 1;
      u32x4 aw;
      aw.x = pack2(accs[m0][0], accs[m0][1]);
      aw.y = pack2(accs[m0][2], accs[m0][3]);
      aw.z = pack2(accs[m1][0], accs[m1][1]);
      aw.w = pack2(accs[m1][2], accs[m1][3]);
      bf16x8 af = __builtin_bit_cast(bf16x8, aw);
      acc_l = __builtin_amdgcn_mfma_f32_16x16x32_bf16(af, vones, acc_l, 0, 0, 0);
      #pragma unroll
      for (int mt2 = 0; mt2 < 4; ++mt2)
        acc_o[mt2] = __builtin_amdgcn_mfma_f32_16x16x32_bf16(af, vf[ks2][mt2], acc_o[mt2], 0, 0, 0);
    }

    __syncthreads();     // drains K(i2+1) gload_lds + all waves done reading K buf
  }

  // ---- epilogue: l4[rg] = acc_l[rg] directly (row q'=4g+rg, replicated over cols) ----
  #pragma unroll
  for (int mt2 = 0; mt2 < 4; ++mt2)
    #pragma unroll
    for (int rg = 0; rg < 4; ++rg) {
      int t = qb + qrow0 + 4 * g + rg;
      out[((size_t)(b * T_ + t)) * (N_HEADS * HEAD_DIM) + h * HEAD_DIM + 16 * mt2 + l15] =
          acc_o[mt2][rg] / acc_l[rg];
    }
}

extern "C" void kernel_launch(void* const* d_in, const int* in_sizes, int n_in,
                              void* d_out, int out_size, void* d_ws, size_t ws_size,
                              hipStream_t stream) {
  const float* q   = (const float*)d_in[0];
  const float* k   = (const float*)d_in[1];
  const float* v   = (const float*)d_in[2];
  const float* qw  = (const float*)d_in[3];
  const float* kw  = (const float*)d_in[4];
  const int*   pos = (const int*)d_in[5];

  u32* kp = (u32*)d_ws;                                    // 2.62 MB
  u32* vp = kp + (size_t)B_ * N_KV * NTILES * TILE_U32;    // 2.62 MB
  float* outp = (float*)d_out;

  // merged prep: 320 V-tile blocks + 320 K-wave blocks (16 rows/wave) in one launch
  prep_kernel<<<2 * B_ * N_KV * NTILES, 256, 0, stream>>>(k, kw, v, pos, kp, vp);
  attn_kernel<<<1600, 256, 0, stream>>>(q, qw, pos, kp, vp, outp);
}

// Round 26
// 52.308 us; speedup vs baseline: 1.2215x; 1.2215x over previous
//
#include <hip/hip_runtime.h>
#include <cmath>

typedef float  f32x4  __attribute__((ext_vector_type(4)));
typedef __bf16 bf16x8 __attribute__((ext_vector_type(8)));
typedef unsigned int u32x4 __attribute__((ext_vector_type(4)));
typedef unsigned int u32x2 __attribute__((ext_vector_type(2)));
typedef unsigned int   u32;
typedef unsigned short u16;

#define HEAD_DIM 64
#define N_HEADS  25
#define N_KV     5
#define WINDOW   1024
#define N_META   128
#define B_       2
#define T_       2048
#define QB       64
#define NTILES   (T_ / 64)
#define TILE_U32 2048               // 64 rows x 32 u32 (8 KB)
// Constant softmax bias: S*0.125*log2e <= (8*1.5)^2*0.125*1.443 ~= 26 (RMSNorm-guaranteed,
// w in [0.5,1.5]). exp2(S-20) <= 64; l <= 6.6e4; min ~= 2^-46 (normal). Scale cancels in O/l.
#define SM_BIAS  (-20.0f)

static __device__ __forceinline__ u16 bf16_bits(float f) {
  __bf16 h = (__bf16)f;
  return __builtin_bit_cast(u16, h);
}
static __device__ __forceinline__ u32 pack2(float lo, float hi) {
  return ((u32)bf16_bits(hi) << 16) | bf16_bits(lo);
}
static __device__ __forceinline__ float fexp2(float x) {
  return __builtin_amdgcn_exp2f(x);    // bare v_exp_f32; exp2(-inf)=0
}
static __device__ __forceinline__ void gload16(const u32* g, u32* l) {
  __builtin_amdgcn_global_load_lds((const __attribute__((address_space(1))) u32*)g,
                                   (__attribute__((address_space(3))) u32*)l, 16, 0, 0);
}

// ---------------- Kernel 1 (merged prep): V-tiles (blk<320) + K 16-row waves (blk>=320) -
// K ws: [b][kvh][tile][key(64)][seg_phys(8) x 4 u32]; seg_phys = seg_log ^ (key&7)
// V ws: [b][kvh][tile][d(64)][32 u32]; col c=16a+8b+2g+e at seg (4a+g)^(d&7), slot 2b+e
__global__ __launch_bounds__(256) void prep_kernel(
    const float* __restrict__ k_in, const float* __restrict__ k_w,
    const float* __restrict__ v_in, const int* __restrict__ pos_ids,
    u32* __restrict__ k_ws, u32* __restrict__ v_ws)
{
  const int blk = blockIdx.x;
  const int tid = threadIdx.x;

  if (blk < B_ * N_KV * NTILES) {
    // ---------------- V transpose tile ----------------
    int tile = blk & (NTILES - 1);
    int bk   = blk >> 5;
    int kvh  = bk % N_KV, b = bk / N_KV;
    int t0   = tile * 64;

    __shared__ u16 Tl[64][72];           // [d][key]

    #pragma unroll
    for (int it = 0; it < 4; ++it) {
      int idx = it * 256 + tid;
      int kl = idx >> 4, dq = idx & 15;
      const float4 f = *(const float4*)&v_in[((size_t)(b * T_ + t0 + kl)) * (N_KV * HEAD_DIM) + kvh * HEAD_DIM + dq * 4];
      Tl[dq * 4 + 0][kl] = bf16_bits(f.x);
      Tl[dq * 4 + 1][kl] = bf16_bits(f.y);
      Tl[dq * 4 + 2][kl] = bf16_bits(f.z);
      Tl[dq * 4 + 3][kl] = bf16_bits(f.w);
    }
    __syncthreads();

    u32* outb = v_ws + (size_t)blk * TILE_U32;
    #pragma unroll
    for (int it = 0; it < 8; ++it) {
      int o = it * 256 + tid;
      int d = o >> 5, c = o & 31;
      u32 w = ((u32)Tl[d][2 * c + 1] << 16) | Tl[d][2 * c];
      int a = c >> 4, bs = (c >> 3) & 1, gp = (c >> 1) & 3, e = c & 1;
      int sp = (4 * a + gp) ^ (d & 7);
      outb[d * 32 + sp * 4 + 2 * bs + e] = w;
    }
    return;
  }

  // ---------------- K RMSNorm + RoPE, 16 rows per wave ----------------
  const int lane = tid & 63, wid = tid >> 6;
  const int l15 = lane & 15, g = lane >> 4;
  const int gw   = (blk - B_ * N_KV * NTILES) * 4 + wid;   // 0..1279
  const int bkvh = gw >> 7;                                // 0..9 = b*5+kvh
  const int sl   = gw & 127;
  const int b    = bkvh / N_KV, kvh = bkvh % N_KV;
  const int t0   = sl * 16;

  const int   jbase = (4 * l15) & 31;
  const float r32   = 0.74989420933f;                      // 10000^(-1/32)
  float fr[4];
  fr[0] = powf(10000.f, -(float)jbase * (1.f / 32.f));
  fr[1] = fr[0] * r32; fr[2] = fr[1] * r32; fr[3] = fr[2] * r32;

  const int t0g = b * T_ + t0;
  int pos_prev = pos_ids[t0g + g];
  float cc[4], sn[4], c4[4], s4[4];
  #pragma unroll
  for (int e = 0; e < 4; ++e) {
    sincosf((float)pos_prev * fr[e], &sn[e], &cc[e]);      // sincosf(x, sin*, cos*)
    sincosf(4.f * fr[e], &s4[e], &c4[e]);
  }
  const float4 wv = *(const float4*)&k_w[4 * l15];
  u32* outb = k_ws + ((size_t)bkvh * NTILES + (t0 >> 6)) * TILE_U32;
  const int klbase = t0 & 63;
  const int sp_c   = l15 >> 1;
  const int slot   = (2 * l15) & 3;

  #pragma unroll
  for (int it = 0; it < 4; ++it) {
    const int row = 4 * it + g;
    if (it) {
      int pos = pos_ids[t0g + row];
      if (__all(pos == pos_prev + 4)) {
        #pragma unroll
        for (int e = 0; e < 4; ++e) {
          float c2 = cc[e] * c4[e] - sn[e] * s4[e];
          sn[e] = sn[e] * c4[e] + cc[e] * s4[e];
          cc[e] = c2;
        }
      } else {
        #pragma unroll
        for (int e = 0; e < 4; ++e) sincosf((float)pos * fr[e], &sn[e], &cc[e]);
      }
      pos_prev = pos;
    }
    const float4 xv = *(const float4*)&k_in[((size_t)(t0g + row)) * (N_KV * HEAD_DIM) + kvh * HEAD_DIM + 4 * l15];
    float ss = xv.x * xv.x + xv.y * xv.y + xv.z * xv.z + xv.w * xv.w;
    ss += __shfl_xor(ss, 1); ss += __shfl_xor(ss, 2);
    ss += __shfl_xor(ss, 4); ss += __shfl_xor(ss, 8);
    const float rn = rsqrtf(ss * (1.f / 64.f) + 1e-6f);
    float y[4] = {wv.x * xv.x * rn, wv.y * xv.y * rn, wv.z * xv.z * rn, wv.w * xv.w * rn};
    float rv[4];
    #pragma unroll
    for (int e = 0; e < 4; ++e) {
      float part = __shfl_xor(y[e], 8);
      rv[e] = (l15 < 8) ? (y[e] * cc[e] - part * sn[e])
                        : (y[e] * cc[e] + part * sn[e]);   // NO scale on K
    }
    const int kl = klbase + row;
    const int sp = sp_c ^ (kl & 7);
    u32x2 w2;
    w2.x = pack2(rv[0], rv[1]);
    w2.y = pack2(rv[2], rv[3]);
    *(u32x2*)&outb[kl * 32 + sp * 4 + slot] = w2;
  }
}

// ---------------- Kernel 2: fused MFMA flash attention (r24: best, 52.3us) -------------
// 16KB LDS, K+V single-buffered; barrier-drained async staging; constant-bias softmax;
// l by MFMA; XCD-affinity + snake decode.
__global__ __launch_bounds__(256, 4) void attn_kernel(
    const float* __restrict__ q_in, const float* __restrict__ q_w,
    const int* __restrict__ pos_ids,
    const u32* __restrict__ kws, const u32* __restrict__ vws,
    float* __restrict__ out)
{
  const int i  = blockIdx.x;
  const int x  = i & 7;
  int k = i >> 3;
  {
    const int row = k >> 5, col = k & 31;
    const int base = row * 32;
    const int span = (200 - base < 32) ? (200 - base) : 32;
    k = base + ((row & 1) ? (span - 1 - col) : col);
  }
  const int gA = (5 * x) >> 2;
  const int a0 = 200 * x - 160 * gA;
  const int nB = 40 + a0;
  int grp, j_;
  if (k < nB) { grp = gA + 1; j_ = k; }
  else        { grp = gA;     j_ = a0 + (k - nB); }
  const int qt  = 31 - j_ / 5;
  const int hh  = j_ % 5;
  const int b   = grp / 5;
  const int kvh = grp % 5;
  const int h   = kvh * 5 + hh;
  const int qb  = qt * QB;
  const int tid = threadIdx.x, wid = tid >> 6, lane = tid & 63;
  const int l15 = lane & 15, g = lane >> 4;
  const int qrow0 = wid * 16;

  __shared__ u32 Ks[TILE_U32];           // K tile, single-buffered
  __shared__ u32 Vt[TILE_U32];           // V^T tile, single-buffered (Q staging pre-loop)

  const int nt    = (qt <= 18) ? (qt + 1) : 19;
  const int shift = qt - 18;

  const size_t kvbase = ((size_t)(b * N_KV + kvh)) * NTILES * TILE_U32;
  const u32* kb = kws + kvbase;
  const u32* vb = vws + kvbase;

  // ---- prologue: issue K(0)->Ks only (Vt hosts Q staging first) ----
  #pragma unroll
  for (int j = 0; j < 2; ++j) {
    int ci = (wid << 1) | j;             // 8 chunks, 2 per wave
    gload16(kb + ci * 256 + lane * 4, &Ks[ci * 256]);
  }

  // ---- Q staging into Vt, 4-rows-parallel: lane (g,l15) row 4it+g, d=4*l15..+3 ----
  {
    const int   jbase = (4 * l15) & 31;
    const float r32   = 0.74989420933f;            // 10000^(-1/32)
    float fr[4];
    fr[0] = powf(10000.f, -(float)jbase * (1.f / 32.f));
    fr[1] = fr[0] * r32; fr[2] = fr[1] * r32; fr[3] = fr[2] * r32;

    const int t0g = b * T_ + qb + qrow0;
    int pos_prev = pos_ids[t0g + g];
    float cc[4], sn[4], c4[4], s4[4];
    #pragma unroll
    for (int e = 0; e < 4; ++e) {
      sincosf((float)pos_prev * fr[e], &sn[e], &cc[e]);   // sincosf(x, sin*, cos*)
      sincosf(4.f * fr[e], &s4[e], &c4[e]);
    }
    const float4 wv = *(const float4*)&q_w[4 * l15];
    #pragma unroll
    for (int it = 0; it < 4; ++it) {
      const int row = 4 * it + g;
      if (it) {
        int pos = pos_ids[t0g + row];
        if (__all(pos == pos_prev + 4)) {
          #pragma unroll
          for (int e = 0; e < 4; ++e) {
            float c2 = cc[e] * c4[e] - sn[e] * s4[e];
            sn[e] = sn[e] * c4[e] + cc[e] * s4[e];
            cc[e] = c2;
          }
        } else {
          #pragma unroll
          for (int e = 0; e < 4; ++e) sincosf((float)pos * fr[e], &sn[e], &cc[e]);
        }
        pos_prev = pos;
      }
      const float4 xv = *(const float4*)&q_in[((size_t)(t0g + row)) * (N_HEADS * HEAD_DIM) + h * HEAD_DIM + 4 * l15];
      float ss = xv.x * xv.x + xv.y * xv.y + xv.z * xv.z + xv.w * xv.w;
      ss += __shfl_xor(ss, 1); ss += __shfl_xor(ss, 2);
      ss += __shfl_xor(ss, 4); ss += __shfl_xor(ss, 8);
      const float rn = rsqrtf(ss * (1.f / 64.f) + 1e-6f);
      float y[4] = {wv.x * xv.x * rn, wv.y * xv.y * rn, wv.z * xv.z * rn, wv.w * xv.w * rn};
      float rv[4];
      #pragma unroll
      for (int e = 0; e < 4; ++e) {
        float part = __shfl_xor(y[e], 8);
        rv[e] = ((l15 < 8) ? (y[e] * cc[e] - part * sn[e])
                           : (y[e] * cc[e] + part * sn[e])) * 0.18033688f;
      }
      u32x2 w2;
      w2.x = pack2(rv[0], rv[1]);
      w2.y = pack2(rv[2], rv[3]);
      *(u32x2*)&Vt[(qrow0 + row) * 32 + 2 * l15] = w2;
    }
  }
  __syncthreads();                       // K(0) drained + Q rows visible in Vt

  bf16x8 qf[2];
  #pragma unroll
  for (int ks = 0; ks < 2; ++ks)
    qf[ks] = *(const bf16x8*)&Vt[(qrow0 + l15) * 32 + 16 * ks + 4 * g];
  __syncthreads();                       // all qf reads done -> Vt free for V(0)

  // ---- issue V(0) into Vt (drained by tile-0 mid-barrier under QK^T+softmax) ----
  #pragma unroll
  for (int j = 0; j < 2; ++j) {
    int ci = (wid << 1) | j;
    gload16(vb + ci * 256 + lane * 4, &Vt[ci * 256]);
  }

  f32x4 acc_o[4];
  #pragma unroll
  for (int mt = 0; mt < 4; ++mt) acc_o[mt] = (f32x4)(0.f);
  f32x4 acc_l = (f32x4)(0.f);            // l by MFMA: P x ones -> row q, replicated cols

  u32x4 onesw;
  onesw.x = 0x3F803F80u; onesw.y = 0x3F803F80u; onesw.z = 0x3F803F80u; onesw.w = 0x3F803F80u;
  const bf16x8 vones = __builtin_bit_cast(bf16x8, onesw);

  const int q_abs = qb + qrow0 + l15;

  for (int i2 = 0; i2 < nt; ++i2) {
    const int k0 = ((qt <= 18 || i2 < 2) ? i2 : i2 + shift) << 6;
    int tn = -1;
    if (i2 + 1 < nt) tn = (qt <= 18 || i2 + 1 < 2) ? (i2 + 1) : (i2 + 1 + shift);

    // ---- S^T - 20 = K·Q^T + C(-20)  (reads Ks = K(i2)) ----
    f32x4 accs[4];
    #pragma unroll
    for (int mt = 0; mt < 4; ++mt) accs[mt] = (f32x4)(SM_BIAS);
    #pragma unroll
    for (int ks = 0; ks < 2; ++ks) {
      #pragma unroll
      for (int mt = 0; mt < 4; ++mt) {
        bf16x8 kf = *(const bf16x8*)&Ks[(16 * mt + l15) * 32 + (((4 * ks + g) ^ (l15 & 7)) << 2)];
        accs[mt] = __builtin_amdgcn_mfma_f32_16x16x32_bf16(kf, qf[ks], accs[mt], 0, 0, 0);
      }
    }

    // ---- mask boundary tiles, then P = exp2(S - 20) ----
    const bool do_mask = (i2 == nt - 1) || (qt >= 18 && i2 == 2);
    if (do_mask) {
      #pragma unroll
      for (int mt = 0; mt < 4; ++mt)
        #pragma unroll
        for (int rg = 0; rg < 4; ++rg) {
          int key = k0 + 16 * mt + 4 * g + rg;
          bool ok = (key <= q_abs) && ((key >= q_abs - (WINDOW - 1)) || (key < N_META));
          accs[mt][rg] = ok ? accs[mt][rg] : -INFINITY;
        }
    }
    #pragma unroll
    for (int mt = 0; mt < 4; ++mt)
      #pragma unroll
      for (int rg = 0; rg < 4; ++rg)
        accs[mt][rg] = fexp2(accs[mt][rg]);      // exp2(-inf) = 0 for masked

    // ---- mid-barrier: drains V(i2) (issued ~1 phase earlier) ----
    __syncthreads();

    // ---- issue K(i2+1) into Ks (all QK^T reads of K(i2) done across waves) ----
    if (tn >= 0) {
      const u32* kt = kb + (size_t)tn * TILE_U32;
      #pragma unroll
      for (int j = 0; j < 2; ++j) {
        int ci = (wid << 1) | j;
        gload16(kt + ci * 256 + lane * 4, &Ks[ci * 256]);
      }
    }

    // ---- O += P·V, l += P·1 (reads Vt = V(i2)) ----
    #pragma unroll
    for (int ks2 = 0; ks2 < 2; ++ks2) {
      const int m0 = 2 * ks2, m1 = 2 * ks2 + 1;
      u32x4 aw;
      aw.x = pack2(accs[m0][0], accs[m0][1]);
      aw.y = pack2(accs[m0][2], accs[m0][3]);
      aw.z = pack2(accs[m1][0], accs[m1][1]);
      aw.w = pack2(accs[m1][2], accs[m1][3]);
      bf16x8 af = __builtin_bit_cast(bf16x8, aw);
      acc_l = __builtin_amdgcn_mfma_f32_16x16x32_bf16(af, vones, acc_l, 0, 0, 0);
      #pragma unroll
      for (int mt2 = 0; mt2 < 4; ++mt2) {
        bf16x8 vf = *(const bf16x8*)&Vt[(16 * mt2 + l15) * 32 + (((4 * ks2 + g) ^ (l15 & 7)) << 2)];
        acc_o[mt2] = __builtin_amdgcn_mfma_f32_16x16x32_bf16(af, vf, acc_o[mt2], 0, 0, 0);
      }
    }

    __syncthreads();     // end-barrier: drains K(i2+1); all V(i2) reads done

    // ---- issue V(i2+1) into Vt (drained by next mid-barrier) ----
    if (tn >= 0) {
      const u32* vt = vb + (size_t)tn * TILE_U32;
      #pragma unroll
      for (int j = 0; j < 2; ++j) {
        int ci = (wid << 1) | j;
        gload16(vt + ci * 256 + lane * 4, &Vt[ci * 256]);
      }
    }
  }

  // ---- epilogue: l4[rg] = acc_l[rg] directly (row q'=4g+rg, replicated over cols) ----
  #pragma unroll
  for (int mt2 = 0; mt2 < 4; ++mt2)
    #pragma unroll
    for (int rg = 0; rg < 4; ++rg) {
      int t = qb + qrow0 + 4 * g + rg;
      out[((size_t)(b * T_ + t)) * (N_HEADS * HEAD_DIM) + h * HEAD_DIM + 16 * mt2 + l15] =
          acc_o[mt2][rg] / acc_l[rg];
    }
}

extern "C" void kernel_launch(void* const* d_in, const int* in_sizes, int n_in,
                              void* d_out, int out_size, void* d_ws, size_t ws_size,
                              hipStream_t stream) {
  const float* q   = (const float*)d_in[0];
  const float* k   = (const float*)d_in[1];
  const float* v   = (const float*)d_in[2];
  const float* qw  = (const float*)d_in[3];
  const float* kw  = (const float*)d_in[4];
  const int*   pos = (const int*)d_in[5];

  u32* kp = (u32*)d_ws;                                    // 2.62 MB
  u32* vp = kp + (size_t)B_ * N_KV * NTILES * TILE_U32;    // 2.62 MB
  float* outp = (float*)d_out;

  // merged prep: 320 V-tile blocks + 320 K-wave blocks (16 rows/wave) in one launch
  prep_kernel<<<2 * B_ * N_KV * NTILES, 256, 0, stream>>>(k, kw, v, pos, kp, vp);
  attn_kernel<<<1600, 256, 0, stream>>>(q, qw, pos, kp, vp, outp);
}